// Round 1
// baseline (542.033 us; speedup 1.0000x reference)
//
#include <hip/hip_runtime.h>

typedef unsigned short u16;
typedef unsigned int u32;
typedef __attribute__((ext_vector_type(8))) short short8;
typedef __attribute__((ext_vector_type(4))) float f32x4;

// ---------- helpers ----------
__device__ __forceinline__ float b2fu(u32 u) {
  union { u32 i; float f; } v; v.i = u << 16; return v.f;
}
__device__ __forceinline__ u16 f2bu(float f) {
  union { float f; u32 i; } v; v.f = f;
  u32 r = (v.i + 0x7fffu + ((v.i >> 16) & 1u)) >> 16;
  return (u16)r;
}
__device__ __forceinline__ void gl_lds16(const void* g, void* l) {
  __builtin_amdgcn_global_load_lds((const __attribute__((address_space(1))) void*)g,
                                   (__attribute__((address_space(3))) void*)l, 16, 0, 0);
}

// ---------- weight fp32 -> bf16 (+concat) ----------
// dst layout (elems of 1M=1<<20): [0,3M)=wq|wk|wv  [3M,4M)=wo  [4M,8M)=gate  [8M,12M)=up  [12M,16M)=down
__global__ __launch_bounds__(256) void cvt_weights(
    const float* __restrict__ wq, const float* __restrict__ wk,
    const float* __restrict__ wv, const float* __restrict__ wo,
    const float* __restrict__ wg, const float* __restrict__ wu,
    const float* __restrict__ wd, u16* __restrict__ dst)
{
  size_t e = ((size_t)blockIdx.x * 256 + threadIdx.x) * 4;
  size_t seg = e >> 20;
  const float* src; size_t base;
  if      (seg == 0) { src = wq; base = 0; }
  else if (seg == 1) { src = wk; base = (size_t)1 << 20; }
  else if (seg == 2) { src = wv; base = (size_t)2 << 20; }
  else if (seg == 3) { src = wo; base = (size_t)3 << 20; }
  else if (seg < 8)  { src = wg; base = (size_t)4 << 20; }
  else if (seg < 12) { src = wu; base = (size_t)8 << 20; }
  else               { src = wd; base = (size_t)12 << 20; }
  float4 v = *(const float4*)(src + (e - base));
  *(ushort4*)(dst + e) = make_ushort4(f2bu(v.x), f2bu(v.y), f2bu(v.z), f2bu(v.w));
}

// ---------- RMSNorm: fp32 [row,1024] -> bf16 ----------
__global__ __launch_bounds__(256) void rmsnorm_kernel(
    const float* __restrict__ x, const float* __restrict__ w, u16* __restrict__ out)
{
  const int row = blockIdx.x;
  const int t = threadIdx.x;
  float4 v = ((const float4*)(x + (size_t)row * 1024))[t];
  float ss = v.x * v.x + v.y * v.y + v.z * v.z + v.w * v.w;
#pragma unroll
  for (int m = 32; m > 0; m >>= 1) ss += __shfl_xor(ss, m, 64);
  __shared__ float red[4];
  if ((t & 63) == 0) red[t >> 6] = ss;
  __syncthreads();
  float tot = red[0] + red[1] + red[2] + red[3];
  float r = rsqrtf(tot * (1.0f / 1024.0f) + 1e-6f);
  float4 wv = ((const float4*)w)[t];
  ushort4 o = make_ushort4(f2bu(v.x * r * wv.x), f2bu(v.y * r * wv.y),
                           f2bu(v.z * r * wv.z), f2bu(v.w * r * wv.w));
  ((ushort4*)(out + (size_t)row * 1024))[t] = o;
}

// ---------- GEMM: C[M,N] = A[M,K](bf16) @ B[N,K](bf16)^T (+bias[N]) (+res[M,N]), fp32 out ----------
template<int TMB, int TNB, bool HAS_BIAS, bool HAS_RES>
__global__ __launch_bounds__(256) void gemm_bt(
    const u16* __restrict__ A, const u16* __restrict__ B, float* __restrict__ C,
    const float* __restrict__ bias, const float* __restrict__ res,
    int M, int N, int K)
{
  constexpr int BK = 32;
  constexpr int WTM = TMB / 2, WTN = TNB / 2;
  constexpr int MT = WTM / 16, NT = WTN / 16;
  __shared__ u16 As[TMB * BK];
  __shared__ u16 Bs[TNB * BK];
  const int t = threadIdx.x;
  const int w = t >> 6, l = t & 63;
  const int wm = (w >> 1) * WTM, wn = (w & 1) * WTN;
  const int lr = l & 15, lq = l >> 4;
  const int tile_m = blockIdx.y * TMB, tile_n = blockIdx.x * TNB;

  f32x4 acc[MT][NT] = {};

  const int sr = t >> 2;
  const int sc8 = (t & 3) * 8;
  const u16* Ab = A + (size_t)(tile_m + sr) * K + sc8;
  const u16* Bb = B + (size_t)(tile_n + sr) * K + sc8;

  for (int kk = 0; kk < K; kk += BK) {
#pragma unroll
    for (int i = 0; i < TMB / 64; ++i)
      gl_lds16(Ab + kk + (size_t)i * 64 * K, &As[t * 8 + i * 2048]);
#pragma unroll
    for (int i = 0; i < TNB / 64; ++i)
      gl_lds16(Bb + kk + (size_t)i * 64 * K, &Bs[t * 8 + i * 2048]);
    __syncthreads();
    short8 af[MT], bfr[NT];
#pragma unroll
    for (int mt = 0; mt < MT; ++mt)
      af[mt] = *(const short8*)&As[(wm + mt * 16 + lr) * BK + lq * 8];
#pragma unroll
    for (int nt = 0; nt < NT; ++nt)
      bfr[nt] = *(const short8*)&Bs[(wn + nt * 16 + lr) * BK + lq * 8];
#pragma unroll
    for (int mt = 0; mt < MT; ++mt)
#pragma unroll
      for (int nt = 0; nt < NT; ++nt)
        acc[mt][nt] = __builtin_amdgcn_mfma_f32_16x16x32_bf16(af[mt], bfr[nt], acc[mt][nt], 0, 0, 0);
    __syncthreads();
  }

#pragma unroll
  for (int nt = 0; nt < NT; ++nt) {
    const int col = tile_n + wn + nt * 16 + lr;
    const float bv = HAS_BIAS ? bias[col] : 0.0f;
#pragma unroll
    for (int mt = 0; mt < MT; ++mt) {
      const int row0 = tile_m + wm + mt * 16 + lq * 4;
#pragma unroll
      for (int r = 0; r < 4; ++r) {
        const size_t off = (size_t)(row0 + r) * N + col;
        float v = acc[mt][nt][r] + bv;
        if (HAS_RES) v += res[off];
        C[off] = v;
      }
    }
  }
}

// ---------- RoPE + split + bf16 cast: qkv fp32 [row,3072] -> q/k/v bf16 [bh,s,64] ----------
__global__ __launch_bounds__(256) void rope_kernel(
    const float* __restrict__ qkv, u16* __restrict__ qb, u16* __restrict__ kb,
    u16* __restrict__ vb)
{
  const int row = blockIdx.x;          // b*1024 + s
  const int s = row & 1023, b = row >> 10;
  const float* qr = qkv + (size_t)row * 3072;
  const int t = threadIdx.x;
#pragma unroll
  for (int e = 0; e < 4; ++e) {
    const int idx = t + e * 256;
    const int h = idx >> 6, d = idx & 63;
    const int i = d & 31;
    // inv_freq = 10000^(-i/32) = 2^(-i*log2(10000)/32)
    const float th = (float)s * exp2f(-0.4152410118609203f * (float)i);
    float sn, cs; sincosf(th, &sn, &cs);
    const float sgn = (d < 32) ? -1.0f : 1.0f;
    const int pidx = (h << 6) | ((d + 32) & 63);
    const float qo = qr[idx] * cs + sgn * qr[pidx] * sn;
    const float ko = qr[1024 + idx] * cs + sgn * qr[1024 + pidx] * sn;
    const size_t ob = (((size_t)(b * 16 + h) << 10) + s) * 64 + d;
    qb[ob] = f2bu(qo);
    kb[ob] = f2bu(ko);
    vb[ob] = f2bu(qr[2048 + idx]);
  }
}

// ---------- sliding-window attention ----------
#define KPAD 76
#define CTX_CASE(T) case T: { \
    ushort4 lo = make_ushort4(f2bu(o_[T*8+0]), f2bu(o_[T*8+1]), f2bu(o_[T*8+2]), f2bu(o_[T*8+3])); \
    ushort4 hi = make_ushort4(f2bu(o_[T*8+4]), f2bu(o_[T*8+5]), f2bu(o_[T*8+6]), f2bu(o_[T*8+7])); \
    *(ushort4*)(cr + T*8) = lo; *(ushort4*)(cr + T*8 + 4) = hi; } break;

__global__ __launch_bounds__(256) void attn_kernel(
    const u16* __restrict__ qb, const u16* __restrict__ kb, const u16* __restrict__ vb,
    float* __restrict__ probs, u16* __restrict__ ctx)
{
  __shared__ u16 kvs[287 * KPAD];           // 43.6 KB, holds K then V
  const int blk = blockIdx.x;
  const int qt = blk & 31, bh = blk >> 5;
  const int b = bh >> 4, h = bh & 15;
  const int q0 = qt * 32;
  const int kstart = (q0 > 255) ? (q0 - 255) : 0;
  const int span = q0 + 32 - kstart;        // <= 287
  const int t = threadIdx.x;
  const int ql = t >> 3, ts = t & 7;
  const int q = q0 + ql;
  const size_t bhS = (size_t)bh << 10;

  // q row -> fp32 regs
  float qv[64];
  {
    const uint4* qg = (const uint4*)(qb + ((bhS + q) << 6));
#pragma unroll
    for (int c = 0; c < 8; ++c) {
      uint4 u = qg[c];
      qv[c*8+0] = b2fu(u.x & 0xffffu); qv[c*8+1] = b2fu(u.x >> 16);
      qv[c*8+2] = b2fu(u.y & 0xffffu); qv[c*8+3] = b2fu(u.y >> 16);
      qv[c*8+4] = b2fu(u.z & 0xffffu); qv[c*8+5] = b2fu(u.z >> 16);
      qv[c*8+6] = b2fu(u.w & 0xffffu); qv[c*8+7] = b2fu(u.w >> 16);
    }
  }
  // stage K window
  {
    const u16* kg = kb + ((bhS + (size_t)kstart) << 6);
    for (int c = t; c < span * 16; c += 256) {
      const int r = c >> 4, o = (c & 15) << 2;
      *(ushort4*)&kvs[r * KPAD + o] = *(const ushort4*)&kg[(r << 6) + o];
    }
  }
  __syncthreads();

  // scores: lane handles keys j = q-255+ts+8i
  float sc[32];
#pragma unroll
  for (int i = 0; i < 32; ++i) {
    const int j = q - 255 + ts + 8 * i;
    float s_ = -1e30f;
    if (j >= 0) {
      const u16* kr = &kvs[(j - kstart) * KPAD];
      float a = 0.0f;
#pragma unroll
      for (int d = 0; d < 64; d += 4) {
        ushort4 u = *(const ushort4*)&kr[d];
        a += qv[d] * b2fu(u.x) + qv[d+1] * b2fu(u.y) + qv[d+2] * b2fu(u.z) + qv[d+3] * b2fu(u.w);
      }
      s_ = a * 0.125f;
    }
    sc[i] = s_;
  }
  // softmax across 8 lanes/query
  float m_ = -1e30f;
#pragma unroll
  for (int i = 0; i < 32; ++i) m_ = fmaxf(m_, sc[i]);
  m_ = fmaxf(m_, __shfl_xor(m_, 1, 64));
  m_ = fmaxf(m_, __shfl_xor(m_, 2, 64));
  m_ = fmaxf(m_, __shfl_xor(m_, 4, 64));
  float sum = 0.0f;
#pragma unroll
  for (int i = 0; i < 32; ++i) { float p = expf(sc[i] - m_); sc[i] = p; sum += p; }
  sum += __shfl_xor(sum, 1, 64);
  sum += __shfl_xor(sum, 2, 64);
  sum += __shfl_xor(sum, 4, 64);
  const float inv = 1.0f / sum;
#pragma unroll
  for (int i = 0; i < 32; ++i) sc[i] *= inv;
  // write window probs (rest of row pre-zeroed by memset)
  {
    float* prow = probs + ((bhS + q) << 10);
#pragma unroll
    for (int i = 0; i < 32; ++i) {
      const int j = q - 255 + ts + 8 * i;
      if (j >= 0) prow[j] = sc[i];
    }
  }
  __syncthreads();
  // stage V window (reuse LDS)
  {
    const u16* vg = vb + ((bhS + (size_t)kstart) << 6);
    for (int c = t; c < span * 16; c += 256) {
      const int r = c >> 4, o = (c & 15) << 2;
      *(ushort4*)&kvs[r * KPAD + o] = *(const ushort4*)&vg[(r << 6) + o];
    }
  }
  __syncthreads();

  float o_[64] = {};
#pragma unroll
  for (int i = 0; i < 32; ++i) {
    const int j = q - 255 + ts + 8 * i;
    if (j < 0) continue;
    const float p = sc[i];
    const u16* vr = &kvs[(j - kstart) * KPAD];
#pragma unroll
    for (int d = 0; d < 64; d += 4) {
      ushort4 u = *(const ushort4*)&vr[d];
      o_[d]   += p * b2fu(u.x);
      o_[d+1] += p * b2fu(u.y);
      o_[d+2] += p * b2fu(u.z);
      o_[d+3] += p * b2fu(u.w);
    }
  }
#pragma unroll
  for (int d = 0; d < 64; ++d) {
    float v = o_[d];
    v += __shfl_xor(v, 1, 64);
    v += __shfl_xor(v, 2, 64);
    v += __shfl_xor(v, 4, 64);
    o_[d] = v;
  }
  // ctx in [b, s, h, d] layout (GEMM-A-ready); each lane writes 8 dims
  u16* cr = ctx + (((size_t)(b * 1024 + q)) << 10) + (h << 6);
  switch (ts) {
    CTX_CASE(0) CTX_CASE(1) CTX_CASE(2) CTX_CASE(3)
    CTX_CASE(4) CTX_CASE(5) CTX_CASE(6) CTX_CASE(7)
  }
}

// ---------- SwiGLU fuse: gu fp32 [row,8192] -> act bf16 [row,4096] ----------
__global__ __launch_bounds__(256) void swiglu_kernel(
    const float* __restrict__ gu, u16* __restrict__ act)
{
  size_t i = ((size_t)blockIdx.x * 256 + threadIdx.x) * 4;
  size_t row = i >> 12, col = i & 4095;
  const float* p = gu + (row << 13) + col;
  float4 g = *(const float4*)p;
  float4 u = *(const float4*)(p + 4096);
  float a0 = g.x / (1.0f + expf(-g.x)) * u.x;
  float a1 = g.y / (1.0f + expf(-g.y)) * u.y;
  float a2 = g.z / (1.0f + expf(-g.z)) * u.z;
  float a3 = g.w / (1.0f + expf(-g.w)) * u.w;
  *(ushort4*)(act + i) = make_ushort4(f2bu(a0), f2bu(a1), f2bu(a2), f2bu(a3));
}

// ---------- launch ----------
extern "C" void kernel_launch(void* const* d_in, const int* in_sizes, int n_in,
                              void* d_out, int out_size, void* d_ws, size_t ws_size,
                              hipStream_t stream) {
  (void)in_sizes; (void)n_in; (void)out_size; (void)ws_size;
  const float* x   = (const float*)d_in[0];
  const float* wq  = (const float*)d_in[1];
  const float* bq  = (const float*)d_in[2];
  const float* wk  = (const float*)d_in[3];
  const float* bk  = (const float*)d_in[4];
  const float* wv  = (const float*)d_in[5];
  const float* bv  = (const float*)d_in[6];
  const float* wo  = (const float*)d_in[7];
  const float* bo  = (const float*)d_in[8];
  const float* anw = (const float*)d_in[9];
  const float* fnw = (const float*)d_in[10];
  const float* wg  = (const float*)d_in[11];
  const float* wu  = (const float*)d_in[12];
  const float* wd  = (const float*)d_in[13];

  char* ws = (char*)d_ws;
  u16*   wbf  = (u16*)ws;                                        // 16M elems bf16 (32MB)
  float* bqkv = (float*)(ws + ((size_t)32 << 20));               // 3072 f32 (pad to 16KB)
  u16*   h1   = (u16*)(ws + ((size_t)32 << 20) + (16 << 10));    // 2M bf16 (4MB)
  char*  R    = ws + ((size_t)36 << 20) + (16 << 10);            // 64MB union region
  float* qkvb = (float*)R;                                       // [2048,3072] f32 (24MB)
  u16*   qbp  = (u16*)(R + ((size_t)24 << 20));                  // 4MB
  u16*   kbp  = (u16*)(R + ((size_t)28 << 20));                  // 4MB
  u16*   vbp  = (u16*)(R + ((size_t)32 << 20));                  // 4MB
  float* gu   = (float*)R;                                       // [2048,8192] f32 (64MB, after attn)
  char*  T2   = R + ((size_t)64 << 20);
  u16*   ctx  = (u16*)T2;                                        // 4MB
  float* x1   = (float*)(T2 + ((size_t)4 << 20));                // 8MB
  u16*   h2   = (u16*)(T2 + ((size_t)12 << 20));                 // 4MB
  u16*   act  = (u16*)(T2 + ((size_t)16 << 20));                 // 16MB   (total ~132MB)

  float* out0  = (float*)d_out;
  float* probs = (float*)d_out + 2097152;

  // weights -> bf16 (+concat), bias concat, zero attn output
  cvt_weights<<<16384, 256, 0, stream>>>(wq, wk, wv, wo, wg, wu, wd, wbf);
  hipMemcpyAsync(bqkv,        bq, 4096, hipMemcpyDeviceToDevice, stream);
  hipMemcpyAsync(bqkv + 1024, bk, 4096, hipMemcpyDeviceToDevice, stream);
  hipMemcpyAsync(bqkv + 2048, bv, 4096, hipMemcpyDeviceToDevice, stream);
  hipMemsetAsync(probs, 0, (size_t)33554432 * 4, stream);

  // attn branch
  rmsnorm_kernel<<<2048, 256, 0, stream>>>(x, anw, h1);
  gemm_bt<128, 128, true, false><<<dim3(24, 16), 256, 0, stream>>>(
      h1, wbf, qkvb, bqkv, nullptr, 2048, 3072, 1024);
  rope_kernel<<<2048, 256, 0, stream>>>(qkvb, qbp, kbp, vbp);
  attn_kernel<<<1024, 256, 0, stream>>>(qbp, kbp, vbp, probs, ctx);
  gemm_bt<64, 128, true, true><<<dim3(8, 32), 256, 0, stream>>>(
      ctx, wbf + ((size_t)3 << 20), x1, bo, x, 2048, 1024, 1024);

  // ffn branch
  rmsnorm_kernel<<<2048, 256, 0, stream>>>(x1, fnw, h2);
  gemm_bt<128, 128, false, false><<<dim3(64, 16), 256, 0, stream>>>(
      h2, wbf + ((size_t)4 << 20), gu, nullptr, nullptr, 2048, 8192, 1024);
  swiglu_kernel<<<8192, 256, 0, stream>>>(gu, act);
  gemm_bt<64, 128, false, true><<<dim3(8, 32), 256, 0, stream>>>(
      act, wbf + ((size_t)12 << 20), out0, nullptr, x1, 2048, 1024, 4096);
}

// Round 2
// 472.570 us; speedup vs baseline: 1.1470x; 1.1470x over previous
//
#include <hip/hip_runtime.h>

typedef unsigned short u16;
typedef unsigned int u32;
typedef __attribute__((ext_vector_type(8))) short short8;
typedef __attribute__((ext_vector_type(4))) float f32x4;

// ---------- helpers ----------
__device__ __forceinline__ float b2fu(u32 u) {
  union { u32 i; float f; } v; v.i = u << 16; return v.f;
}
__device__ __forceinline__ u16 f2bu(float f) {
  union { float f; u32 i; } v; v.f = f;
  u32 r = (v.i + 0x7fffu + ((v.i >> 16) & 1u)) >> 16;
  return (u16)r;
}
__device__ __forceinline__ void gl_lds16(const void* g, void* l) {
  __builtin_amdgcn_global_load_lds((const __attribute__((address_space(1))) void*)g,
                                   (__attribute__((address_space(3))) void*)l, 16, 0, 0);
}
// 16B-worth LDS load from an 8-byte-aligned address (rows padded to odd*4 u16)
__device__ __forceinline__ short8 ld_lds_b8(const u16* p) {
  uint2 a = *(const uint2*)p;
  uint2 b = *(const uint2*)(p + 4);
  union { u32 u[4]; short8 s; } v;
  v.u[0] = a.x; v.u[1] = a.y; v.u[2] = b.x; v.u[3] = b.y;
  return v.s;
}

// ---------- weight fp32 -> bf16 (+concat) ----------
__global__ __launch_bounds__(256) void cvt_weights(
    const float* __restrict__ wq, const float* __restrict__ wk,
    const float* __restrict__ wv, const float* __restrict__ wo,
    const float* __restrict__ wg, const float* __restrict__ wu,
    const float* __restrict__ wd, u16* __restrict__ dst)
{
  size_t e = ((size_t)blockIdx.x * 256 + threadIdx.x) * 4;
  size_t seg = e >> 20;
  const float* src; size_t base;
  if      (seg == 0) { src = wq; base = 0; }
  else if (seg == 1) { src = wk; base = (size_t)1 << 20; }
  else if (seg == 2) { src = wv; base = (size_t)2 << 20; }
  else if (seg == 3) { src = wo; base = (size_t)3 << 20; }
  else if (seg < 8)  { src = wg; base = (size_t)4 << 20; }
  else if (seg < 12) { src = wu; base = (size_t)8 << 20; }
  else               { src = wd; base = (size_t)12 << 20; }
  float4 v = *(const float4*)(src + (e - base));
  *(ushort4*)(dst + e) = make_ushort4(f2bu(v.x), f2bu(v.y), f2bu(v.z), f2bu(v.w));
}

// ---------- RMSNorm: fp32 [row,1024] -> bf16 ----------
__global__ __launch_bounds__(256) void rmsnorm_kernel(
    const float* __restrict__ x, const float* __restrict__ w, u16* __restrict__ out)
{
  const int row = blockIdx.x;
  const int t = threadIdx.x;
  float4 v = ((const float4*)(x + (size_t)row * 1024))[t];
  float ss = v.x * v.x + v.y * v.y + v.z * v.z + v.w * v.w;
#pragma unroll
  for (int m = 32; m > 0; m >>= 1) ss += __shfl_xor(ss, m, 64);
  __shared__ float red[4];
  if ((t & 63) == 0) red[t >> 6] = ss;
  __syncthreads();
  float tot = red[0] + red[1] + red[2] + red[3];
  float r = rsqrtf(tot * (1.0f / 1024.0f) + 1e-6f);
  float4 wv = ((const float4*)w)[t];
  ushort4 o = make_ushort4(f2bu(v.x * r * wv.x), f2bu(v.y * r * wv.y),
                           f2bu(v.z * r * wv.z), f2bu(v.w * r * wv.w));
  ((ushort4*)(out + (size_t)row * 1024))[t] = o;
}

// ---------- GEMM: C[M,N] = A[M,K](bf16) @ B[N,K](bf16)^T (+bias[N]) (+res[M,N]) ----------
template<int TMB, int TNB, bool HAS_BIAS, bool HAS_RES>
__global__ __launch_bounds__(256) void gemm_bt(
    const u16* __restrict__ A, const u16* __restrict__ B, float* __restrict__ C,
    const float* __restrict__ bias, const float* __restrict__ res,
    int M, int N, int K)
{
  constexpr int BK = 32;
  constexpr int WTM = TMB / 2, WTN = TNB / 2;
  constexpr int MT = WTM / 16, NT = WTN / 16;
  __shared__ u16 As[TMB * BK];
  __shared__ u16 Bs[TNB * BK];
  const int t = threadIdx.x;
  const int w = t >> 6, l = t & 63;
  const int wm = (w >> 1) * WTM, wn = (w & 1) * WTN;
  const int lr = l & 15, lq = l >> 4;
  const int tile_m = blockIdx.y * TMB, tile_n = blockIdx.x * TNB;

  f32x4 acc[MT][NT] = {};

  const int sr = t >> 2;
  const int sc8 = (t & 3) * 8;
  const u16* Ab = A + (size_t)(tile_m + sr) * K + sc8;
  const u16* Bb = B + (size_t)(tile_n + sr) * K + sc8;

  for (int kk = 0; kk < K; kk += BK) {
#pragma unroll
    for (int i = 0; i < TMB / 64; ++i)
      gl_lds16(Ab + kk + (size_t)i * 64 * K, &As[t * 8 + i * 2048]);
#pragma unroll
    for (int i = 0; i < TNB / 64; ++i)
      gl_lds16(Bb + kk + (size_t)i * 64 * K, &Bs[t * 8 + i * 2048]);
    __syncthreads();
    short8 af[MT], bfr[NT];
#pragma unroll
    for (int mt = 0; mt < MT; ++mt)
      af[mt] = *(const short8*)&As[(wm + mt * 16 + lr) * BK + lq * 8];
#pragma unroll
    for (int nt = 0; nt < NT; ++nt)
      bfr[nt] = *(const short8*)&Bs[(wn + nt * 16 + lr) * BK + lq * 8];
#pragma unroll
    for (int mt = 0; mt < MT; ++mt)
#pragma unroll
      for (int nt = 0; nt < NT; ++nt)
        acc[mt][nt] = __builtin_amdgcn_mfma_f32_16x16x32_bf16(af[mt], bfr[nt], acc[mt][nt], 0, 0, 0);
    __syncthreads();
  }

#pragma unroll
  for (int nt = 0; nt < NT; ++nt) {
    const int col = tile_n + wn + nt * 16 + lr;
    const float bv = HAS_BIAS ? bias[col] : 0.0f;
#pragma unroll
    for (int mt = 0; mt < MT; ++mt) {
      const int row0 = tile_m + wm + mt * 16 + lq * 4;
#pragma unroll
      for (int r = 0; r < 4; ++r) {
        const size_t off = (size_t)(row0 + r) * N + col;
        float v = acc[mt][nt][r] + bv;
        if (HAS_RES) v += res[off];
        C[off] = v;
      }
    }
  }
}

// ---------- RoPE + split + bf16 cast ----------
__global__ __launch_bounds__(256) void rope_kernel(
    const float* __restrict__ qkv, u16* __restrict__ qb, u16* __restrict__ kb,
    u16* __restrict__ vb)
{
  const int row = blockIdx.x;          // b*1024 + s
  const int s = row & 1023, b = row >> 10;
  const float* qr = qkv + (size_t)row * 3072;
  const int t = threadIdx.x;
#pragma unroll
  for (int e = 0; e < 4; ++e) {
    const int idx = t + e * 256;
    const int h = idx >> 6, d = idx & 63;
    const int i = d & 31;
    const float th = (float)s * exp2f(-0.4152410118609203f * (float)i);
    float sn, cs; sincosf(th, &sn, &cs);
    const float sgn = (d < 32) ? -1.0f : 1.0f;
    const int pidx = (h << 6) | ((d + 32) & 63);
    const float qo = qr[idx] * cs + sgn * qr[pidx] * sn;
    const float ko = qr[1024 + idx] * cs + sgn * qr[1024 + pidx] * sn;
    const size_t ob = (((size_t)(b * 16 + h) << 10) + s) * 64 + d;
    qb[ob] = f2bu(qo);
    kb[ob] = f2bu(ko);
    vb[ob] = f2bu(qr[2048 + idx]);
  }
}

// ---------- MFMA sliding-window attention ----------
// Block = (bh, 32-query tile). LDS: K [288][68] (reused as P [32][292]) + V [288][68].
#define KP 68     // K/V row pad (u16): stride 136B = 34 words -> bank 2*lr, conflict-free
#define PP 292    // P row pad (u16): stride 584B = 146 words -> bank 18*lr, conflict-free

__global__ __launch_bounds__(256) void attn_kernel(
    const u16* __restrict__ qb, const u16* __restrict__ kb, const u16* __restrict__ vb,
    float* __restrict__ probs, u16* __restrict__ ctx)
{
  __shared__ u16 Kbuf[288 * KP];     // 39168 B, becomes Pbuf after scores
  __shared__ u16 Vbuf[288 * KP];     // 39168 B
  __shared__ float smax[2][32];
  __shared__ float ssum[2][32];
  u16* Pbuf = Kbuf;

  const int blk = blockIdx.x;
  const int qt = blk & 31, bh = blk >> 5;
  const int b = bh >> 4, h = bh & 15;
  const int q0 = qt << 5;
  const int kstart = (q0 > 255) ? (q0 - 255) : 0;
  const int span = q0 + 32 - kstart;           // <= 287
  const int t = threadIdx.x;
  const int w = t >> 6, l = t & 63;
  const int lr = l & 15, lq = l >> 4;
  const int mw = w & 1, nh = w >> 1;           // m-tile, n-half
  const size_t bhS = (size_t)bh << 10;

  // ---- stage K and V (zero-fill beyond span; keeps PV NaN-free) ----
  {
    const u16* kg = kb + ((bhS + (size_t)kstart) << 6);
    const u16* vg = vb + ((bhS + (size_t)kstart) << 6);
    for (int idx = t; idx < 288 * 8; idx += 256) {
      const int r = idx >> 3, c = (idx & 7) << 3;
      uint4 kv4 = make_uint4(0, 0, 0, 0), vv4 = make_uint4(0, 0, 0, 0);
      if (r < span) {
        kv4 = *(const uint4*)&kg[(r << 6) + c];
        vv4 = *(const uint4*)&vg[(r << 6) + c];
      }
      *(uint2*)&Kbuf[r * KP + c]     = make_uint2(kv4.x, kv4.y);
      *(uint2*)&Kbuf[r * KP + c + 4] = make_uint2(kv4.z, kv4.w);
      *(uint2*)&Vbuf[r * KP + c]     = make_uint2(vv4.x, vv4.y);
      *(uint2*)&Vbuf[r * KP + c + 4] = make_uint2(vv4.z, vv4.w);
    }
  }
  // Q A-fragments straight from global: A[m=lr][k=lq*8+j], ksteps d=0,32
  short8 qa0, qa1;
  {
    const u16* qrow = qb + ((bhS + (size_t)(q0 + mw * 16 + lr)) << 6) + lq * 8;
    qa0 = *(const short8*)qrow;
    qa1 = *(const short8*)(qrow + 32);
  }
  __syncthreads();

  // ---- QK^T: wave (mw,nh) covers n-tiles nt = nh + 2*i, i=0..8 ----
  f32x4 acc[9];
#pragma unroll
  for (int i = 0; i < 9; ++i) acc[i] = (f32x4){0.f, 0.f, 0.f, 0.f};
#pragma unroll
  for (int i = 0; i < 9; ++i) {
    const int nt = nh + 2 * i;
    const u16* kr = &Kbuf[(nt * 16 + lr) * KP + lq * 8];
    short8 kf0 = ld_lds_b8(kr);
    short8 kf1 = ld_lds_b8(kr + 32);
    acc[i] = __builtin_amdgcn_mfma_f32_16x16x32_bf16(qa0, kf0, acc[i], 0, 0, 0);
    acc[i] = __builtin_amdgcn_mfma_f32_16x16x32_bf16(qa1, kf1, acc[i], 0, 0, 0);
  }

  // ---- mask + softmax (rows live on the 16 lanes of a quad) ----
  const int rbase = mw * 16 + lq * 4;
  float rmax[4] = {-1e30f, -1e30f, -1e30f, -1e30f};
#pragma unroll
  for (int i = 0; i < 9; ++i) {
    const int jg = kstart + (nh + 2 * i) * 16 + lr;
#pragma unroll
    for (int r = 0; r < 4; ++r) {
      const int q = q0 + rbase + r;
      const bool valid = (jg >= q - 255) && (jg <= q);
      const float v = valid ? acc[i][r] * 0.125f : -1e30f;
      acc[i][r] = v;
      rmax[r] = fmaxf(rmax[r], v);
    }
  }
#pragma unroll
  for (int r = 0; r < 4; ++r) {
    float m_ = rmax[r];
    m_ = fmaxf(m_, __shfl_xor(m_, 1, 64));
    m_ = fmaxf(m_, __shfl_xor(m_, 2, 64));
    m_ = fmaxf(m_, __shfl_xor(m_, 4, 64));
    m_ = fmaxf(m_, __shfl_xor(m_, 8, 64));
    rmax[r] = m_;
  }
  if (lr == 0) {
#pragma unroll
    for (int r = 0; r < 4; ++r) smax[nh][rbase + r] = rmax[r];
  }
  __syncthreads();                                   // also closes all Kbuf reads
#pragma unroll
  for (int r = 0; r < 4; ++r)
    rmax[r] = fmaxf(smax[0][rbase + r], smax[1][rbase + r]);
  float rsum[4] = {0.f, 0.f, 0.f, 0.f};
#pragma unroll
  for (int i = 0; i < 9; ++i)
#pragma unroll
    for (int r = 0; r < 4; ++r) {
      const float p = exp2f((acc[i][r] - rmax[r]) * 1.44269504f);
      acc[i][r] = p;
      rsum[r] += p;
    }
#pragma unroll
  for (int r = 0; r < 4; ++r) {
    float s_ = rsum[r];
    s_ += __shfl_xor(s_, 1, 64);
    s_ += __shfl_xor(s_, 2, 64);
    s_ += __shfl_xor(s_, 4, 64);
    s_ += __shfl_xor(s_, 8, 64);
    rsum[r] = s_;
  }
  if (lr == 0) {
#pragma unroll
    for (int r = 0; r < 4; ++r) ssum[nh][rbase + r] = rsum[r];
  }
  __syncthreads();

  // ---- normalize, P -> LDS (bf16, A-operand layout source) ----
  float inv4[4];
#pragma unroll
  for (int r = 0; r < 4; ++r)
    inv4[r] = 1.0f / (ssum[0][rbase + r] + ssum[1][rbase + r]);
#pragma unroll
  for (int i = 0; i < 9; ++i) {
    const int nt = nh + 2 * i;
#pragma unroll
    for (int r = 0; r < 4; ++r)
      Pbuf[(rbase + r) * PP + nt * 16 + lr] = f2bu(acc[i][r] * inv4[r]);
  }
  __syncthreads();

  // ---- write full prob rows (zeros outside window) ----
  {
    const int row = t >> 3;
    const int q = q0 + row;
    const int c0 = (t & 7) << 7;
    const int lo = q - 255;
    float* prow = probs + ((bhS + (size_t)q) << 10) + c0;
    const u16* pr = &Pbuf[row * PP];
#pragma unroll 4
    for (int cc = 0; cc < 128; cc += 4) {
      const int c = c0 + cc;
      float4 o;
      o.x = (c + 0 >= lo && c + 0 <= q) ? b2fu(pr[c + 0 - kstart]) : 0.0f;
      o.y = (c + 1 >= lo && c + 1 <= q) ? b2fu(pr[c + 1 - kstart]) : 0.0f;
      o.z = (c + 2 >= lo && c + 2 <= q) ? b2fu(pr[c + 2 - kstart]) : 0.0f;
      o.w = (c + 3 >= lo && c + 3 <= q) ? b2fu(pr[c + 3 - kstart]) : 0.0f;
      *(float4*)&prow[cc] = o;
    }
  }

  // ---- PV: wave (mw, n0) -> output rows mw*16.., cols d = (n0+nn)*16.. ----
  const int n0 = (w >> 1) * 2;
  f32x4 oacc[2] = {};
#pragma unroll
  for (int ks = 0; ks < 9; ++ks) {
    short8 pa = ld_lds_b8(&Pbuf[(mw * 16 + lr) * PP + ks * 32 + lq * 8]);
#pragma unroll
    for (int nn = 0; nn < 2; ++nn) {
      const int d = (n0 + nn) * 16 + lr;
      union { u16 u[8]; short8 s; } bf_;
#pragma unroll
      for (int jj = 0; jj < 8; ++jj)
        bf_.u[jj] = Vbuf[(ks * 32 + lq * 8 + jj) * KP + d];
      oacc[nn] = __builtin_amdgcn_mfma_f32_16x16x32_bf16(pa, bf_.s, oacc[nn], 0, 0, 0);
    }
  }
  // ctx in [b, s, h*64+d] (o-proj A-ready)
#pragma unroll
  for (int nn = 0; nn < 2; ++nn) {
    const int d = (n0 + nn) * 16 + lr;
#pragma unroll
    for (int r = 0; r < 4; ++r) {
      const int q = q0 + rbase + r;
      ctx[(((size_t)(b * 1024 + q)) << 10) + (h << 6) + d] = f2bu(oacc[nn][r]);
    }
  }
}

// ---------- SwiGLU fuse ----------
__global__ __launch_bounds__(256) void swiglu_kernel(
    const float* __restrict__ gu, u16* __restrict__ act)
{
  size_t i = ((size_t)blockIdx.x * 256 + threadIdx.x) * 4;
  size_t row = i >> 12, col = i & 4095;
  const float* p = gu + (row << 13) + col;
  float4 g = *(const float4*)p;
  float4 u = *(const float4*)(p + 4096);
  float a0 = g.x / (1.0f + expf(-g.x)) * u.x;
  float a1 = g.y / (1.0f + expf(-g.y)) * u.y;
  float a2 = g.z / (1.0f + expf(-g.z)) * u.z;
  float a3 = g.w / (1.0f + expf(-g.w)) * u.w;
  *(ushort4*)(act + i) = make_ushort4(f2bu(a0), f2bu(a1), f2bu(a2), f2bu(a3));
}

// ---------- launch ----------
extern "C" void kernel_launch(void* const* d_in, const int* in_sizes, int n_in,
                              void* d_out, int out_size, void* d_ws, size_t ws_size,
                              hipStream_t stream) {
  (void)in_sizes; (void)n_in; (void)out_size; (void)ws_size;
  const float* x   = (const float*)d_in[0];
  const float* wq  = (const float*)d_in[1];
  const float* bq  = (const float*)d_in[2];
  const float* wk  = (const float*)d_in[3];
  const float* bk  = (const float*)d_in[4];
  const float* wv  = (const float*)d_in[5];
  const float* bv  = (const float*)d_in[6];
  const float* wo  = (const float*)d_in[7];
  const float* bo  = (const float*)d_in[8];
  const float* anw = (const float*)d_in[9];
  const float* fnw = (const float*)d_in[10];
  const float* wg  = (const float*)d_in[11];
  const float* wu  = (const float*)d_in[12];
  const float* wd  = (const float*)d_in[13];

  char* ws = (char*)d_ws;
  u16*   wbf  = (u16*)ws;                                        // 16M bf16 (32MB)
  float* bqkv = (float*)(ws + ((size_t)32 << 20));               // 3072 f32
  u16*   h1   = (u16*)(ws + ((size_t)32 << 20) + (16 << 10));    // 2M bf16 (4MB)
  char*  R    = ws + ((size_t)36 << 20) + (16 << 10);
  float* qkvb = (float*)R;                                       // [2048,3072] f32 (24MB)
  u16*   qbp  = (u16*)(R + ((size_t)24 << 20));                  // 4MB
  u16*   kbp  = (u16*)(R + ((size_t)28 << 20));                  // 4MB
  u16*   vbp  = (u16*)(R + ((size_t)32 << 20));                  // 4MB
  float* gu   = (float*)R;                                       // [2048,8192] f32 (64MB, reuses qkv region)
  char*  T2   = R + ((size_t)64 << 20);
  u16*   ctx  = (u16*)T2;                                        // 4MB
  float* x1   = (float*)(T2 + ((size_t)4 << 20));                // 8MB
  u16*   h2   = (u16*)(T2 + ((size_t)12 << 20));                 // 4MB
  u16*   act  = (u16*)(T2 + ((size_t)16 << 20));                 // 16MB

  float* out0  = (float*)d_out;
  float* probs = (float*)d_out + 2097152;

  cvt_weights<<<16384, 256, 0, stream>>>(wq, wk, wv, wo, wg, wu, wd, wbf);
  hipMemcpyAsync(bqkv,        bq, 4096, hipMemcpyDeviceToDevice, stream);
  hipMemcpyAsync(bqkv + 1024, bk, 4096, hipMemcpyDeviceToDevice, stream);
  hipMemcpyAsync(bqkv + 2048, bv, 4096, hipMemcpyDeviceToDevice, stream);

  // attn branch
  rmsnorm_kernel<<<2048, 256, 0, stream>>>(x, anw, h1);
  gemm_bt<64, 128, true, false><<<dim3(24, 32), 256, 0, stream>>>(
      h1, wbf, qkvb, bqkv, nullptr, 2048, 3072, 1024);
  rope_kernel<<<2048, 256, 0, stream>>>(qkvb, qbp, kbp, vbp);
  attn_kernel<<<1024, 256, 0, stream>>>(qbp, kbp, vbp, probs, ctx);
  gemm_bt<64, 64, true, true><<<dim3(16, 32), 256, 0, stream>>>(
      ctx, wbf + ((size_t)3 << 20), x1, bo, x, 2048, 1024, 1024);

  // ffn branch
  rmsnorm_kernel<<<2048, 256, 0, stream>>>(x1, fnw, h2);
  gemm_bt<128, 128, false, false><<<dim3(64, 16), 256, 0, stream>>>(
      h2, wbf + ((size_t)4 << 20), gu, nullptr, nullptr, 2048, 8192, 1024);
  swiglu_kernel<<<8192, 256, 0, stream>>>(gu, act);
  gemm_bt<64, 64, false, true><<<dim3(16, 32), 256, 0, stream>>>(
      act, wbf + ((size_t)12 << 20), out0, nullptr, x1, 2048, 1024, 4096);
}

// Round 3
// 461.102 us; speedup vs baseline: 1.1755x; 1.0249x over previous
//
#include <hip/hip_runtime.h>

typedef unsigned short u16;
typedef unsigned int u32;
typedef __attribute__((ext_vector_type(8))) short short8;
typedef __attribute__((ext_vector_type(4))) float f32x4;

// ---------- helpers ----------
__device__ __forceinline__ float b2fu(u32 u) {
  union { u32 i; float f; } v; v.i = u << 16; return v.f;
}
__device__ __forceinline__ u16 f2bu(float f) {
  union { float f; u32 i; } v; v.f = f;
  u32 r = (v.i + 0x7fffu + ((v.i >> 16) & 1u)) >> 16;
  return (u16)r;
}
__device__ __forceinline__ void gl_lds16(const void* g, void* l) {
  __builtin_amdgcn_global_load_lds((const __attribute__((address_space(1))) void*)g,
                                   (__attribute__((address_space(3))) void*)l, 16, 0, 0);
}
__device__ __forceinline__ short8 ld_lds_b8(const u16* p) {
  uint2 a = *(const uint2*)p;
  uint2 b = *(const uint2*)(p + 4);
  union { u32 u[4]; short8 s; } v;
  v.u[0] = a.x; v.u[1] = a.y; v.u[2] = b.x; v.u[3] = b.y;
  return v.s;
}

// ---------- weight fp32 -> bf16 (+concat, gate/up interleave) ----------
// dst (1M=1<<20 elems): [0,3M)=wq|wk|wv  [3M,4M)=wo  [4M,12M)=gate/up interleaved
//   per 16 rows (comb row (r>>4)*32+(r&15) gate, +16 up)  [12M,16M)=down
__global__ __launch_bounds__(256) void cvt_weights(
    const float* __restrict__ wq, const float* __restrict__ wk,
    const float* __restrict__ wv, const float* __restrict__ wo,
    const float* __restrict__ wg, const float* __restrict__ wu,
    const float* __restrict__ wd, u16* __restrict__ dst)
{
  size_t e = ((size_t)blockIdx.x * 256 + threadIdx.x) * 4;
  size_t seg = e >> 20;
  const float* src; size_t soff;
  if      (seg == 0) { src = wq; soff = e; }
  else if (seg == 1) { src = wk; soff = e - ((size_t)1 << 20); }
  else if (seg == 2) { src = wv; soff = e - ((size_t)2 << 20); }
  else if (seg == 3) { src = wo; soff = e - ((size_t)3 << 20); }
  else if (seg < 12) {
    size_t idx = e - ((size_t)4 << 20);
    int rc = (int)(idx >> 10);            // combined row 0..8191
    int col = (int)(idx & 1023);
    int bi = rc >> 5, j = rc & 31;
    if (j < 16) { src = wg; soff = (size_t)(bi * 16 + j) * 1024 + col; }
    else        { src = wu; soff = (size_t)(bi * 16 + j - 16) * 1024 + col; }
  }
  else { src = wd; soff = e - ((size_t)12 << 20); }
  float4 v = *(const float4*)(src + soff);
  *(ushort4*)(dst + e) = make_ushort4(f2bu(v.x), f2bu(v.y), f2bu(v.z), f2bu(v.w));
}

// ---------- RMSNorm: fp32 [row,1024] -> bf16 ----------
__global__ __launch_bounds__(256) void rmsnorm_kernel(
    const float* __restrict__ x, const float* __restrict__ w, u16* __restrict__ out)
{
  const int row = blockIdx.x;
  const int t = threadIdx.x;
  float4 v = ((const float4*)(x + (size_t)row * 1024))[t];
  float ss = v.x * v.x + v.y * v.y + v.z * v.z + v.w * v.w;
#pragma unroll
  for (int m = 32; m > 0; m >>= 1) ss += __shfl_xor(ss, m, 64);
  __shared__ float red[4];
  if ((t & 63) == 0) red[t >> 6] = ss;
  __syncthreads();
  float tot = red[0] + red[1] + red[2] + red[3];
  float r = rsqrtf(tot * (1.0f / 1024.0f) + 1e-6f);
  float4 wv = ((const float4*)w)[t];
  ushort4 o = make_ushort4(f2bu(v.x * r * wv.x), f2bu(v.y * r * wv.y),
                           f2bu(v.z * r * wv.z), f2bu(v.w * r * wv.w));
  ((ushort4*)(out + (size_t)row * 1024))[t] = o;
}

// ---------- GEMM: C[M,N] = A[M,K](bf16) @ B[N,K](bf16)^T, fused epilogues ----------
// EPI 0: fp32 C (+bias) (+res)      EPI 1: QKV->rope->q/k/v bf16 [bh,s,64] (+bias)
// EPI 2: gate/up interleaved -> silu(g)*u -> act bf16 [M, N/2]
template<int TMB, int TNB, int EPI, bool HAS_BIAS, bool HAS_RES>
__global__ __launch_bounds__(256) void gemm_bt(
    const u16* __restrict__ A, const u16* __restrict__ B, float* __restrict__ C,
    const float* __restrict__ bias, const float* __restrict__ res,
    int M, int N, int K,
    u16* __restrict__ P0, u16* __restrict__ P1, u16* __restrict__ P2)
{
  constexpr int BK = 32;
  constexpr int WTM = TMB / 2, WTN = TNB / 2;
  constexpr int MT = WTM / 16, NT = WTN / 16;
  __shared__ u16 As[TMB * BK];
  __shared__ u16 Bs[TNB * BK];
  const int t = threadIdx.x;
  const int w = t >> 6, l = t & 63;
  const int wm = (w >> 1) * WTM, wn = (w & 1) * WTN;
  const int lr = l & 15, lq = l >> 4;
  const int tile_m = blockIdx.y * TMB, tile_n = blockIdx.x * TNB;

  f32x4 acc[MT][NT] = {};

  const int sr = t >> 2;
  const int sc8 = (t & 3) * 8;
  const u16* Ab = A + (size_t)(tile_m + sr) * K + sc8;
  const u16* Bb = B + (size_t)(tile_n + sr) * K + sc8;

  for (int kk = 0; kk < K; kk += BK) {
#pragma unroll
    for (int i = 0; i < TMB / 64; ++i)
      gl_lds16(Ab + kk + (size_t)i * 64 * K, &As[t * 8 + i * 2048]);
#pragma unroll
    for (int i = 0; i < TNB / 64; ++i)
      gl_lds16(Bb + kk + (size_t)i * 64 * K, &Bs[t * 8 + i * 2048]);
    __syncthreads();
    short8 af[MT], bfr[NT];
#pragma unroll
    for (int mt = 0; mt < MT; ++mt)
      af[mt] = *(const short8*)&As[(wm + mt * 16 + lr) * BK + lq * 8];
#pragma unroll
    for (int nt = 0; nt < NT; ++nt)
      bfr[nt] = *(const short8*)&Bs[(wn + nt * 16 + lr) * BK + lq * 8];
#pragma unroll
    for (int mt = 0; mt < MT; ++mt)
#pragma unroll
      for (int nt = 0; nt < NT; ++nt)
        acc[mt][nt] = __builtin_amdgcn_mfma_f32_16x16x32_bf16(af[mt], bfr[nt], acc[mt][nt], 0, 0, 0);
    __syncthreads();
  }

  if (EPI == 0) {
#pragma unroll
    for (int nt = 0; nt < NT; ++nt) {
      const int col = tile_n + wn + nt * 16 + lr;
      const float bv = HAS_BIAS ? bias[col] : 0.0f;
#pragma unroll
      for (int mt = 0; mt < MT; ++mt) {
        const int row0 = tile_m + wm + mt * 16 + lq * 4;
#pragma unroll
        for (int r = 0; r < 4; ++r) {
          const size_t off = (size_t)(row0 + r) * N + col;
          float v = acc[mt][nt][r] + bv;
          if (HAS_RES) v += res[off];
          C[off] = v;
        }
      }
    }
  } else if (EPI == 1) {
    // cols tile_n+wn .. +63 = one head's 64 dims of q (seg 0), k (seg 1), or v (seg 2)
    const int colbase = tile_n + wn;
    const int seg = colbase >> 10;
    const int h = (colbase >> 6) & 15;
    u16* dstb = (seg == 0) ? P0 : (seg == 1) ? P1 : P2;
    float bv[NT];
#pragma unroll
    for (int nt = 0; nt < NT; ++nt) bv[nt] = bias[colbase + nt * 16 + lr];
#pragma unroll
    for (int mt = 0; mt < MT; ++mt) {
      const int row0 = tile_m + wm + mt * 16 + lq * 4;
#pragma unroll
      for (int r = 0; r < 4; ++r) {
        const int row = row0 + r;
        const int s = row & 1023, b = row >> 10;
        u16* dst = dstb + (((size_t)(b * 16 + h) << 10) + s) * 64;
        if (seg < 2) {
#pragma unroll
          for (int np = 0; np < 2; ++np) {
            const int i = np * 16 + lr;
            const float th = (float)s * exp2f(-0.4152410118609203f * (float)i);
            float sn, cs; __sincosf(th, &sn, &cs);
            const float g0 = acc[mt][np][r] + bv[np];
            const float g2 = acc[mt][np + 2][r] + bv[np + 2];
            dst[i]      = f2bu(g0 * cs - g2 * sn);
            dst[i + 32] = f2bu(g2 * cs + g0 * sn);
          }
        } else {
#pragma unroll
          for (int nt = 0; nt < NT; ++nt)
            dst[nt * 16 + lr] = f2bu(acc[mt][nt][r] + bv[nt]);
        }
      }
    }
  } else {  // EPI == 2: gate/up interleaved per 16 cols -> silu(g)*u
#pragma unroll
    for (int nt = 0; nt < NT; nt += 2) {
      const int feat = (((tile_n + wn + nt * 16) >> 5) << 4) + lr;
#pragma unroll
      for (int mt = 0; mt < MT; ++mt) {
        const int row0 = tile_m + wm + mt * 16 + lq * 4;
#pragma unroll
        for (int r = 0; r < 4; ++r) {
          const float g = acc[mt][nt][r];
          const float u = acc[mt][nt + 1][r];
          const float a = g / (1.0f + __expf(-g)) * u;
          P0[(size_t)(row0 + r) * (N >> 1) + feat] = f2bu(a);
        }
      }
    }
  }
}

// ---------- MFMA sliding-window attention ----------
#define KP 68
#define PP 292

__global__ __launch_bounds__(256) void attn_kernel(
    const u16* __restrict__ qb, const u16* __restrict__ kb, const u16* __restrict__ vb,
    float* __restrict__ probs, u16* __restrict__ ctx)
{
  __shared__ u16 Kbuf[288 * KP];
  __shared__ u16 Vbuf[288 * KP];
  __shared__ float smax[2][32];
  __shared__ float ssum[2][32];
  u16* Pbuf = Kbuf;

  const int blk = blockIdx.x;
  const int qt = blk & 31, bh = blk >> 5;
  const int b = bh >> 4, h = bh & 15;
  const int q0 = qt << 5;
  const int kstart = (q0 > 255) ? (q0 - 255) : 0;
  const int span = q0 + 32 - kstart;
  const int t = threadIdx.x;
  const int w = t >> 6, l = t & 63;
  const int lr = l & 15, lq = l >> 4;
  const int mw = w & 1, nh = w >> 1;
  const size_t bhS = (size_t)bh << 10;

  {
    const u16* kg = kb + ((bhS + (size_t)kstart) << 6);
    const u16* vg = vb + ((bhS + (size_t)kstart) << 6);
    for (int idx = t; idx < 288 * 8; idx += 256) {
      const int r = idx >> 3, c = (idx & 7) << 3;
      uint4 kv4 = make_uint4(0, 0, 0, 0), vv4 = make_uint4(0, 0, 0, 0);
      if (r < span) {
        kv4 = *(const uint4*)&kg[(r << 6) + c];
        vv4 = *(const uint4*)&vg[(r << 6) + c];
      }
      *(uint2*)&Kbuf[r * KP + c]     = make_uint2(kv4.x, kv4.y);
      *(uint2*)&Kbuf[r * KP + c + 4] = make_uint2(kv4.z, kv4.w);
      *(uint2*)&Vbuf[r * KP + c]     = make_uint2(vv4.x, vv4.y);
      *(uint2*)&Vbuf[r * KP + c + 4] = make_uint2(vv4.z, vv4.w);
    }
  }
  short8 qa0, qa1;
  {
    const u16* qrow = qb + ((bhS + (size_t)(q0 + mw * 16 + lr)) << 6) + lq * 8;
    qa0 = *(const short8*)qrow;
    qa1 = *(const short8*)(qrow + 32);
  }
  __syncthreads();

  f32x4 acc[9];
#pragma unroll
  for (int i = 0; i < 9; ++i) acc[i] = (f32x4){0.f, 0.f, 0.f, 0.f};
#pragma unroll
  for (int i = 0; i < 9; ++i) {
    const int nt = nh + 2 * i;
    const u16* kr = &Kbuf[(nt * 16 + lr) * KP + lq * 8];
    short8 kf0 = ld_lds_b8(kr);
    short8 kf1 = ld_lds_b8(kr + 32);
    acc[i] = __builtin_amdgcn_mfma_f32_16x16x32_bf16(qa0, kf0, acc[i], 0, 0, 0);
    acc[i] = __builtin_amdgcn_mfma_f32_16x16x32_bf16(qa1, kf1, acc[i], 0, 0, 0);
  }

  const int rbase = mw * 16 + lq * 4;
  float rmax[4] = {-1e30f, -1e30f, -1e30f, -1e30f};
#pragma unroll
  for (int i = 0; i < 9; ++i) {
    const int jg = kstart + (nh + 2 * i) * 16 + lr;
#pragma unroll
    for (int r = 0; r < 4; ++r) {
      const int q = q0 + rbase + r;
      const bool valid = (jg >= q - 255) && (jg <= q);
      const float v = valid ? acc[i][r] * 0.125f : -1e30f;
      acc[i][r] = v;
      rmax[r] = fmaxf(rmax[r], v);
    }
  }
#pragma unroll
  for (int r = 0; r < 4; ++r) {
    float m_ = rmax[r];
    m_ = fmaxf(m_, __shfl_xor(m_, 1, 64));
    m_ = fmaxf(m_, __shfl_xor(m_, 2, 64));
    m_ = fmaxf(m_, __shfl_xor(m_, 4, 64));
    m_ = fmaxf(m_, __shfl_xor(m_, 8, 64));
    rmax[r] = m_;
  }
  if (lr == 0) {
#pragma unroll
    for (int r = 0; r < 4; ++r) smax[nh][rbase + r] = rmax[r];
  }
  __syncthreads();
#pragma unroll
  for (int r = 0; r < 4; ++r)
    rmax[r] = fmaxf(smax[0][rbase + r], smax[1][rbase + r]);
  float rsum[4] = {0.f, 0.f, 0.f, 0.f};
#pragma unroll
  for (int i = 0; i < 9; ++i)
#pragma unroll
    for (int r = 0; r < 4; ++r) {
      const float p = exp2f((acc[i][r] - rmax[r]) * 1.44269504f);
      acc[i][r] = p;
      rsum[r] += p;
    }
#pragma unroll
  for (int r = 0; r < 4; ++r) {
    float s_ = rsum[r];
    s_ += __shfl_xor(s_, 1, 64);
    s_ += __shfl_xor(s_, 2, 64);
    s_ += __shfl_xor(s_, 4, 64);
    s_ += __shfl_xor(s_, 8, 64);
    rsum[r] = s_;
  }
  if (lr == 0) {
#pragma unroll
    for (int r = 0; r < 4; ++r) ssum[nh][rbase + r] = rsum[r];
  }
  __syncthreads();

  float inv4[4];
#pragma unroll
  for (int r = 0; r < 4; ++r)
    inv4[r] = 1.0f / (ssum[0][rbase + r] + ssum[1][rbase + r]);
#pragma unroll
  for (int i = 0; i < 9; ++i) {
    const int nt = nh + 2 * i;
#pragma unroll
    for (int r = 0; r < 4; ++r)
      Pbuf[(rbase + r) * PP + nt * 16 + lr] = f2bu(acc[i][r] * inv4[r]);
  }
  __syncthreads();

  {
    const int row = t >> 3;
    const int q = q0 + row;
    const int c0 = (t & 7) << 7;
    const int lo = q - 255;
    float* prow = probs + ((bhS + (size_t)q) << 10) + c0;
    const u16* pr = &Pbuf[row * PP];
#pragma unroll 4
    for (int cc = 0; cc < 128; cc += 4) {
      const int c = c0 + cc;
      float4 o;
      o.x = (c + 0 >= lo && c + 0 <= q) ? b2fu(pr[c + 0 - kstart]) : 0.0f;
      o.y = (c + 1 >= lo && c + 1 <= q) ? b2fu(pr[c + 1 - kstart]) : 0.0f;
      o.z = (c + 2 >= lo && c + 2 <= q) ? b2fu(pr[c + 2 - kstart]) : 0.0f;
      o.w = (c + 3 >= lo && c + 3 <= q) ? b2fu(pr[c + 3 - kstart]) : 0.0f;
      *(float4*)&prow[cc] = o;
    }
  }

  const int n0 = (w >> 1) * 2;
  f32x4 oacc[2] = {};
#pragma unroll
  for (int ks = 0; ks < 9; ++ks) {
    short8 pa = ld_lds_b8(&Pbuf[(mw * 16 + lr) * PP + ks * 32 + lq * 8]);
#pragma unroll
    for (int nn = 0; nn < 2; ++nn) {
      const int d = (n0 + nn) * 16 + lr;
      union { u16 u[8]; short8 s; } bf_;
#pragma unroll
      for (int jj = 0; jj < 8; ++jj)
        bf_.u[jj] = Vbuf[(ks * 32 + lq * 8 + jj) * KP + d];
      oacc[nn] = __builtin_amdgcn_mfma_f32_16x16x32_bf16(pa, bf_.s, oacc[nn], 0, 0, 0);
    }
  }
#pragma unroll
  for (int nn = 0; nn < 2; ++nn) {
    const int d = (n0 + nn) * 16 + lr;
#pragma unroll
    for (int r = 0; r < 4; ++r) {
      const int q = q0 + rbase + r;
      ctx[(((size_t)(b * 1024 + q)) << 10) + (h << 6) + d] = f2bu(oacc[nn][r]);
    }
  }
}

// ---------- launch ----------
extern "C" void kernel_launch(void* const* d_in, const int* in_sizes, int n_in,
                              void* d_out, int out_size, void* d_ws, size_t ws_size,
                              hipStream_t stream) {
  (void)in_sizes; (void)n_in; (void)out_size; (void)ws_size;
  const float* x   = (const float*)d_in[0];
  const float* wq  = (const float*)d_in[1];
  const float* bq  = (const float*)d_in[2];
  const float* wk  = (const float*)d_in[3];
  const float* bk  = (const float*)d_in[4];
  const float* wv  = (const float*)d_in[5];
  const float* bv  = (const float*)d_in[6];
  const float* wo  = (const float*)d_in[7];
  const float* bo  = (const float*)d_in[8];
  const float* anw = (const float*)d_in[9];
  const float* fnw = (const float*)d_in[10];
  const float* wg  = (const float*)d_in[11];
  const float* wu  = (const float*)d_in[12];
  const float* wd  = (const float*)d_in[13];

  char* ws = (char*)d_ws;
  u16*   wbf  = (u16*)ws;                                        // 16M bf16 (32MB)
  float* bqkv = (float*)(ws + ((size_t)32 << 20));               // 3072 f32
  u16*   h1   = (u16*)(ws + ((size_t)32 << 20) + (16 << 10));    // 4MB
  char*  R    = ws + ((size_t)36 << 20) + (16 << 10);
  u16*   qbp  = (u16*)R;                                         // 4MB
  u16*   kbp  = (u16*)(R + ((size_t)4 << 20));                   // 4MB
  u16*   vbp  = (u16*)(R + ((size_t)8 << 20));                   // 4MB
  u16*   ctx  = (u16*)(R + ((size_t)12 << 20));                  // 4MB
  float* x1   = (float*)(R + ((size_t)16 << 20));                // 8MB
  u16*   h2   = (u16*)(R + ((size_t)24 << 20));                  // 4MB
  u16*   act  = (u16*)(R + ((size_t)28 << 20));                  // 16MB

  float* out0  = (float*)d_out;
  float* probs = (float*)d_out + 2097152;

  cvt_weights<<<16384, 256, 0, stream>>>(wq, wk, wv, wo, wg, wu, wd, wbf);
  hipMemcpyAsync(bqkv,        bq, 4096, hipMemcpyDeviceToDevice, stream);
  hipMemcpyAsync(bqkv + 1024, bk, 4096, hipMemcpyDeviceToDevice, stream);
  hipMemcpyAsync(bqkv + 2048, bv, 4096, hipMemcpyDeviceToDevice, stream);

  // attn branch
  rmsnorm_kernel<<<2048, 256, 0, stream>>>(x, anw, h1);
  gemm_bt<128, 128, 1, true, false><<<dim3(24, 16), 256, 0, stream>>>(
      h1, wbf, nullptr, bqkv, nullptr, 2048, 3072, 1024, qbp, kbp, vbp);
  attn_kernel<<<1024, 256, 0, stream>>>(qbp, kbp, vbp, probs, ctx);
  gemm_bt<64, 128, 0, true, true><<<dim3(8, 32), 256, 0, stream>>>(
      ctx, wbf + ((size_t)3 << 20), x1, bo, x, 2048, 1024, 1024,
      nullptr, nullptr, nullptr);

  // ffn branch
  rmsnorm_kernel<<<2048, 256, 0, stream>>>(x1, fnw, h2);
  gemm_bt<128, 128, 2, false, false><<<dim3(64, 16), 256, 0, stream>>>(
      h2, wbf + ((size_t)4 << 20), nullptr, nullptr, nullptr, 2048, 8192, 1024,
      act, nullptr, nullptr);
  gemm_bt<64, 128, 0, false, true><<<dim3(8, 32), 256, 0, stream>>>(
      act, wbf + ((size_t)12 << 20), out0, nullptr, x1, 2048, 1024, 4096,
      nullptr, nullptr, nullptr);
}

// Round 4
// 423.112 us; speedup vs baseline: 1.2811x; 1.0898x over previous
//
#include <hip/hip_runtime.h>

typedef unsigned short u16;
typedef unsigned int u32;
typedef __attribute__((ext_vector_type(8))) short short8;
typedef __attribute__((ext_vector_type(4))) float f32x4;

// ---------- helpers ----------
__device__ __forceinline__ float b2fu(u32 u) {
  union { u32 i; float f; } v; v.i = u << 16; return v.f;
}
__device__ __forceinline__ u16 f2bu(float f) {
  union { float f; u32 i; } v; v.f = f;
  u32 r = (v.i + 0x7fffu + ((v.i >> 16) & 1u)) >> 16;
  return (u16)r;
}
__device__ __forceinline__ void gl_lds16(const void* g, void* l) {
  __builtin_amdgcn_global_load_lds((const __attribute__((address_space(1))) void*)g,
                                   (__attribute__((address_space(3))) void*)l, 16, 0, 0);
}
__device__ __forceinline__ short8 ld_lds_b8(const u16* p) {
  uint2 a = *(const uint2*)p;
  uint2 b = *(const uint2*)(p + 4);
  union { u32 u[4]; short8 s; } v;
  v.u[0] = a.x; v.u[1] = a.y; v.u[2] = b.x; v.u[3] = b.y;
  return v.s;
}

// ---------- weight fp32 -> bf16 (+concat, gate/up interleave) + bias concat ----------
// dst (1M=1<<20 elems): [0,3M)=wq|wk|wv  [3M,4M)=wo  [4M,12M)=gate/up interleaved
//   per 16 rows (comb row (r>>4)*32+(r&15) gate, +16 up)  [12M,16M)=down
// blocks 16384..16386: copy bq|bk|bv -> bqkv (fp32)
__global__ __launch_bounds__(256) void cvt_weights(
    const float* __restrict__ wq, const float* __restrict__ wk,
    const float* __restrict__ wv, const float* __restrict__ wo,
    const float* __restrict__ wg, const float* __restrict__ wu,
    const float* __restrict__ wd, u16* __restrict__ dst,
    const float* __restrict__ bq, const float* __restrict__ bk,
    const float* __restrict__ bv, float* __restrict__ bqkv)
{
  if (blockIdx.x >= 16384) {
    const int s = blockIdx.x - 16384;
    const float* bsrc = (s == 0) ? bq : (s == 1) ? bk : bv;
    const int o = threadIdx.x * 4;
    *(float4*)(bqkv + s * 1024 + o) = *(const float4*)(bsrc + o);
    return;
  }
  size_t e = ((size_t)blockIdx.x * 256 + threadIdx.x) * 4;
  size_t seg = e >> 20;
  const float* src; size_t soff;
  if      (seg == 0) { src = wq; soff = e; }
  else if (seg == 1) { src = wk; soff = e - ((size_t)1 << 20); }
  else if (seg == 2) { src = wv; soff = e - ((size_t)2 << 20); }
  else if (seg == 3) { src = wo; soff = e - ((size_t)3 << 20); }
  else if (seg < 12) {
    size_t idx = e - ((size_t)4 << 20);
    int rc = (int)(idx >> 10);
    int col = (int)(idx & 1023);
    int bi = rc >> 5, j = rc & 31;
    if (j < 16) { src = wg; soff = (size_t)(bi * 16 + j) * 1024 + col; }
    else        { src = wu; soff = (size_t)(bi * 16 + j - 16) * 1024 + col; }
  }
  else { src = wd; soff = e - ((size_t)12 << 20); }
  float4 v = *(const float4*)(src + soff);
  *(ushort4*)(dst + e) = make_ushort4(f2bu(v.x), f2bu(v.y), f2bu(v.z), f2bu(v.w));
}

// ---------- RMSNorm: fp32 [row,1024] -> bf16 ----------
__global__ __launch_bounds__(256) void rmsnorm_kernel(
    const float* __restrict__ x, const float* __restrict__ w, u16* __restrict__ out)
{
  const int row = blockIdx.x;
  const int t = threadIdx.x;
  float4 v = ((const float4*)(x + (size_t)row * 1024))[t];
  float ss = v.x * v.x + v.y * v.y + v.z * v.z + v.w * v.w;
#pragma unroll
  for (int m = 32; m > 0; m >>= 1) ss += __shfl_xor(ss, m, 64);
  __shared__ float red[4];
  if ((t & 63) == 0) red[t >> 6] = ss;
  __syncthreads();
  float tot = red[0] + red[1] + red[2] + red[3];
  float r = rsqrtf(tot * (1.0f / 1024.0f) + 1e-6f);
  float4 wv = ((const float4*)w)[t];
  ushort4 o = make_ushort4(f2bu(v.x * r * wv.x), f2bu(v.y * r * wv.y),
                           f2bu(v.z * r * wv.z), f2bu(v.w * r * wv.w));
  ((ushort4*)(out + (size_t)row * 1024))[t] = o;
}

// ---------- GEMM: C[M,N] = A[M,K](bf16) @ B[N,K](bf16)^T, fused epilogues ----------
// EPI 0: fp32 C (+bias) (+res)   EPI 1: QKV->rope->q/k/v bf16 [bh,s,64] (+bias)
// EPI 2: gate/up interleaved -> silu(g)*u -> act bf16 [M, N/2]
// SPLIT: blockIdx.z selects K-slice [z*K,(z+1)*K) of row stride lda; C offset z*M*N (EPI0, no bias/res)
template<int TMB, int TNB, int EPI, bool HAS_BIAS, bool HAS_RES, bool SPLIT>
__global__ __launch_bounds__(256) void gemm_bt(
    const u16* __restrict__ A, const u16* __restrict__ B, float* __restrict__ C,
    const float* __restrict__ bias, const float* __restrict__ res,
    int M, int N, int K, int lda,
    u16* __restrict__ P0, u16* __restrict__ P1, u16* __restrict__ P2)
{
  constexpr int BK = 32;
  constexpr int WTM = TMB / 2, WTN = TNB / 2;
  constexpr int MT = WTM / 16, NT = WTN / 16;
  __shared__ u16 As[TMB * BK];
  __shared__ u16 Bs[TNB * BK];
  const int t = threadIdx.x;
  const int w = t >> 6, l = t & 63;
  const int wm = (w >> 1) * WTM, wn = (w & 1) * WTN;
  const int lr = l & 15, lq = l >> 4;
  const int tile_m = blockIdx.y * TMB, tile_n = blockIdx.x * TNB;
  const int kb = SPLIT ? blockIdx.z * K : 0;
  if (SPLIT) C += (size_t)blockIdx.z * M * N;

  f32x4 acc[MT][NT] = {};

  const int sr = t >> 2;
  const int sc8 = (t & 3) * 8;
  const u16* Ab = A + (size_t)(tile_m + sr) * lda + kb + sc8;
  const u16* Bb = B + (size_t)(tile_n + sr) * lda + kb + sc8;

  for (int kk = 0; kk < K; kk += BK) {
#pragma unroll
    for (int i = 0; i < TMB / 64; ++i)
      gl_lds16(Ab + kk + (size_t)i * 64 * lda, &As[t * 8 + i * 2048]);
#pragma unroll
    for (int i = 0; i < TNB / 64; ++i)
      gl_lds16(Bb + kk + (size_t)i * 64 * lda, &Bs[t * 8 + i * 2048]);
    __syncthreads();
    short8 af[MT], bfr[NT];
#pragma unroll
    for (int mt = 0; mt < MT; ++mt)
      af[mt] = *(const short8*)&As[(wm + mt * 16 + lr) * BK + lq * 8];
#pragma unroll
    for (int nt = 0; nt < NT; ++nt)
      bfr[nt] = *(const short8*)&Bs[(wn + nt * 16 + lr) * BK + lq * 8];
#pragma unroll
    for (int mt = 0; mt < MT; ++mt)
#pragma unroll
      for (int nt = 0; nt < NT; ++nt)
        acc[mt][nt] = __builtin_amdgcn_mfma_f32_16x16x32_bf16(af[mt], bfr[nt], acc[mt][nt], 0, 0, 0);
    __syncthreads();
  }

  if (EPI == 0) {
#pragma unroll
    for (int nt = 0; nt < NT; ++nt) {
      const int col = tile_n + wn + nt * 16 + lr;
      const float bv = HAS_BIAS ? bias[col] : 0.0f;
#pragma unroll
      for (int mt = 0; mt < MT; ++mt) {
        const int row0 = tile_m + wm + mt * 16 + lq * 4;
#pragma unroll
        for (int r = 0; r < 4; ++r) {
          const size_t off = (size_t)(row0 + r) * N + col;
          float v = acc[mt][nt][r] + bv;
          if (HAS_RES) v += res[off];
          C[off] = v;
        }
      }
    }
  } else if (EPI == 1) {
    const int colbase = tile_n + wn;
    const int seg = colbase >> 10;
    const int h = (colbase >> 6) & 15;
    u16* dstb = (seg == 0) ? P0 : (seg == 1) ? P1 : P2;
    float bv[NT];
#pragma unroll
    for (int nt = 0; nt < NT; ++nt) bv[nt] = bias[colbase + nt * 16 + lr];
#pragma unroll
    for (int mt = 0; mt < MT; ++mt) {
      const int row0 = tile_m + wm + mt * 16 + lq * 4;
#pragma unroll
      for (int r = 0; r < 4; ++r) {
        const int row = row0 + r;
        const int s = row & 1023, b = row >> 10;
        u16* dst = dstb + (((size_t)(b * 16 + h) << 10) + s) * 64;
        if (seg < 2) {
#pragma unroll
          for (int np = 0; np < 2; ++np) {
            const int i = np * 16 + lr;
            const float th = (float)s * exp2f(-0.4152410118609203f * (float)i);
            float sn, cs; __sincosf(th, &sn, &cs);
            const float g0 = acc[mt][np][r] + bv[np];
            const float g2 = acc[mt][np + 2][r] + bv[np + 2];
            dst[i]      = f2bu(g0 * cs - g2 * sn);
            dst[i + 32] = f2bu(g2 * cs + g0 * sn);
          }
        } else {
#pragma unroll
          for (int nt = 0; nt < NT; ++nt)
            dst[nt * 16 + lr] = f2bu(acc[mt][nt][r] + bv[nt]);
        }
      }
    }
  } else {  // EPI == 2
#pragma unroll
    for (int nt = 0; nt < NT; nt += 2) {
      const int feat = (((tile_n + wn + nt * 16) >> 5) << 4) + lr;
#pragma unroll
      for (int mt = 0; mt < MT; ++mt) {
        const int row0 = tile_m + wm + mt * 16 + lq * 4;
#pragma unroll
        for (int r = 0; r < 4; ++r) {
          const float g = acc[mt][nt][r];
          const float u = acc[mt][nt + 1][r];
          const float a = g / (1.0f + __expf(-g)) * u;
          P0[(size_t)(row0 + r) * (N >> 1) + feat] = f2bu(a);
        }
      }
    }
  }
}

// ---------- split-K reduce: out = res + p0+p1+p2+p3 ----------
__global__ __launch_bounds__(256) void reduce4_kernel(
    const float* __restrict__ p, const float* __restrict__ res, float* __restrict__ out)
{
  const size_t i = ((size_t)blockIdx.x * 256 + threadIdx.x) * 4;
  float4 a = *(const float4*)(p + i);
  float4 b = *(const float4*)(p + i + 2097152);
  float4 c = *(const float4*)(p + i + 2 * 2097152);
  float4 d = *(const float4*)(p + i + 3 * 2097152);
  float4 r = *(const float4*)(res + i);
  float4 o;
  o.x = r.x + a.x + b.x + c.x + d.x;
  o.y = r.y + a.y + b.y + c.y + d.y;
  o.z = r.z + a.z + b.z + c.z + d.z;
  o.w = r.w + a.w + b.w + c.w + d.w;
  *(float4*)(out + i) = o;
}

// ---------- MFMA sliding-window attention ----------
#define KP 68
#define PP 292

__global__ __launch_bounds__(256) void attn_kernel(
    const u16* __restrict__ qb, const u16* __restrict__ kb, const u16* __restrict__ vb,
    float* __restrict__ probs, u16* __restrict__ ctx)
{
  __shared__ u16 Kbuf[288 * KP];
  __shared__ u16 Vbuf[288 * KP];
  __shared__ float smax[2][32];
  __shared__ float ssum[2][32];
  u16* Pbuf = Kbuf;

  const int blk = blockIdx.x;
  const int qt = blk & 31, bh = blk >> 5;
  const int b = bh >> 4, h = bh & 15;
  const int q0 = qt << 5;
  const int kstart = (q0 > 255) ? (q0 - 255) : 0;
  const int span = q0 + 32 - kstart;
  const int t = threadIdx.x;
  const int w = t >> 6, l = t & 63;
  const int lr = l & 15, lq = l >> 4;
  const int mw = w & 1, nh = w >> 1;
  const size_t bhS = (size_t)bh << 10;

  {
    const u16* kg = kb + ((bhS + (size_t)kstart) << 6);
    const u16* vg = vb + ((bhS + (size_t)kstart) << 6);
    for (int idx = t; idx < 288 * 8; idx += 256) {
      const int r = idx >> 3, c = (idx & 7) << 3;
      uint4 kv4 = make_uint4(0, 0, 0, 0), vv4 = make_uint4(0, 0, 0, 0);
      if (r < span) {
        kv4 = *(const uint4*)&kg[(r << 6) + c];
        vv4 = *(const uint4*)&vg[(r << 6) + c];
      }
      *(uint2*)&Kbuf[r * KP + c]     = make_uint2(kv4.x, kv4.y);
      *(uint2*)&Kbuf[r * KP + c + 4] = make_uint2(kv4.z, kv4.w);
      *(uint2*)&Vbuf[r * KP + c]     = make_uint2(vv4.x, vv4.y);
      *(uint2*)&Vbuf[r * KP + c + 4] = make_uint2(vv4.z, vv4.w);
    }
  }
  short8 qa0, qa1;
  {
    const u16* qrow = qb + ((bhS + (size_t)(q0 + mw * 16 + lr)) << 6) + lq * 8;
    qa0 = *(const short8*)qrow;
    qa1 = *(const short8*)(qrow + 32);
  }
  __syncthreads();

  f32x4 acc[9];
#pragma unroll
  for (int i = 0; i < 9; ++i) acc[i] = (f32x4){0.f, 0.f, 0.f, 0.f};
#pragma unroll
  for (int i = 0; i < 9; ++i) {
    const int nt = nh + 2 * i;
    const u16* kr = &Kbuf[(nt * 16 + lr) * KP + lq * 8];
    short8 kf0 = ld_lds_b8(kr);
    short8 kf1 = ld_lds_b8(kr + 32);
    acc[i] = __builtin_amdgcn_mfma_f32_16x16x32_bf16(qa0, kf0, acc[i], 0, 0, 0);
    acc[i] = __builtin_amdgcn_mfma_f32_16x16x32_bf16(qa1, kf1, acc[i], 0, 0, 0);
  }

  const int rbase = mw * 16 + lq * 4;
  float rmax[4] = {-1e30f, -1e30f, -1e30f, -1e30f};
#pragma unroll
  for (int i = 0; i < 9; ++i) {
    const int jg = kstart + (nh + 2 * i) * 16 + lr;
#pragma unroll
    for (int r = 0; r < 4; ++r) {
      const int q = q0 + rbase + r;
      const bool valid = (jg >= q - 255) && (jg <= q);
      const float v = valid ? acc[i][r] * 0.125f : -1e30f;
      acc[i][r] = v;
      rmax[r] = fmaxf(rmax[r], v);
    }
  }
#pragma unroll
  for (int r = 0; r < 4; ++r) {
    float m_ = rmax[r];
    m_ = fmaxf(m_, __shfl_xor(m_, 1, 64));
    m_ = fmaxf(m_, __shfl_xor(m_, 2, 64));
    m_ = fmaxf(m_, __shfl_xor(m_, 4, 64));
    m_ = fmaxf(m_, __shfl_xor(m_, 8, 64));
    rmax[r] = m_;
  }
  if (lr == 0) {
#pragma unroll
    for (int r = 0; r < 4; ++r) smax[nh][rbase + r] = rmax[r];
  }
  __syncthreads();
#pragma unroll
  for (int r = 0; r < 4; ++r)
    rmax[r] = fmaxf(smax[0][rbase + r], smax[1][rbase + r]);
  float rsum[4] = {0.f, 0.f, 0.f, 0.f};
#pragma unroll
  for (int i = 0; i < 9; ++i)
#pragma unroll
    for (int r = 0; r < 4; ++r) {
      const float p = exp2f((acc[i][r] - rmax[r]) * 1.44269504f);
      acc[i][r] = p;
      rsum[r] += p;
    }
#pragma unroll
  for (int r = 0; r < 4; ++r) {
    float s_ = rsum[r];
    s_ += __shfl_xor(s_, 1, 64);
    s_ += __shfl_xor(s_, 2, 64);
    s_ += __shfl_xor(s_, 4, 64);
    s_ += __shfl_xor(s_, 8, 64);
    rsum[r] = s_;
  }
  if (lr == 0) {
#pragma unroll
    for (int r = 0; r < 4; ++r) ssum[nh][rbase + r] = rsum[r];
  }
  __syncthreads();

  float inv4[4];
#pragma unroll
  for (int r = 0; r < 4; ++r)
    inv4[r] = 1.0f / (ssum[0][rbase + r] + ssum[1][rbase + r]);
#pragma unroll
  for (int i = 0; i < 9; ++i) {
    const int nt = nh + 2 * i;
#pragma unroll
    for (int r = 0; r < 4; ++r)
      Pbuf[(rbase + r) * PP + nt * 16 + lr] = f2bu(acc[i][r] * inv4[r]);
  }
  __syncthreads();

  {
    const int row = t >> 3;
    const int q = q0 + row;
    const int c0 = (t & 7) << 7;
    const int lo = q - 255;
    float* prow = probs + ((bhS + (size_t)q) << 10) + c0;
    const u16* pr = &Pbuf[row * PP];
#pragma unroll 4
    for (int cc = 0; cc < 128; cc += 4) {
      const int c = c0 + cc;
      float4 o;
      o.x = (c + 0 >= lo && c + 0 <= q) ? b2fu(pr[c + 0 - kstart]) : 0.0f;
      o.y = (c + 1 >= lo && c + 1 <= q) ? b2fu(pr[c + 1 - kstart]) : 0.0f;
      o.z = (c + 2 >= lo && c + 2 <= q) ? b2fu(pr[c + 2 - kstart]) : 0.0f;
      o.w = (c + 3 >= lo && c + 3 <= q) ? b2fu(pr[c + 3 - kstart]) : 0.0f;
      *(float4*)&prow[cc] = o;
    }
  }

  const int n0 = (w >> 1) * 2;
  f32x4 oacc[2] = {};
#pragma unroll
  for (int ks = 0; ks < 9; ++ks) {
    short8 pa = ld_lds_b8(&Pbuf[(mw * 16 + lr) * PP + ks * 32 + lq * 8]);
#pragma unroll
    for (int nn = 0; nn < 2; ++nn) {
      const int d = (n0 + nn) * 16 + lr;
      union { u16 u[8]; short8 s; } bf_;
#pragma unroll
      for (int jj = 0; jj < 8; ++jj)
        bf_.u[jj] = Vbuf[(ks * 32 + lq * 8 + jj) * KP + d];
      oacc[nn] = __builtin_amdgcn_mfma_f32_16x16x32_bf16(pa, bf_.s, oacc[nn], 0, 0, 0);
    }
  }
#pragma unroll
  for (int nn = 0; nn < 2; ++nn) {
    const int d = (n0 + nn) * 16 + lr;
#pragma unroll
    for (int r = 0; r < 4; ++r) {
      const int q = q0 + rbase + r;
      ctx[(((size_t)(b * 1024 + q)) << 10) + (h << 6) + d] = f2bu(oacc[nn][r]);
    }
  }
}

// ---------- launch ----------
extern "C" void kernel_launch(void* const* d_in, const int* in_sizes, int n_in,
                              void* d_out, int out_size, void* d_ws, size_t ws_size,
                              hipStream_t stream) {
  (void)in_sizes; (void)n_in; (void)out_size; (void)ws_size;
  const float* x   = (const float*)d_in[0];
  const float* wq  = (const float*)d_in[1];
  const float* bq  = (const float*)d_in[2];
  const float* wk  = (const float*)d_in[3];
  const float* bk  = (const float*)d_in[4];
  const float* wv  = (const float*)d_in[5];
  const float* bv  = (const float*)d_in[6];
  const float* wo  = (const float*)d_in[7];
  const float* bo  = (const float*)d_in[8];
  const float* anw = (const float*)d_in[9];
  const float* fnw = (const float*)d_in[10];
  const float* wg  = (const float*)d_in[11];
  const float* wu  = (const float*)d_in[12];
  const float* wd  = (const float*)d_in[13];

  char* ws = (char*)d_ws;
  u16*   wbf  = (u16*)ws;                                        // 32MB
  float* bqkv = (float*)(ws + ((size_t)32 << 20));               // 12KB
  u16*   h1   = (u16*)(ws + ((size_t)32 << 20) + (16 << 10));    // 4MB
  char*  R    = ws + ((size_t)36 << 20) + (16 << 10);
  u16*   qbp  = (u16*)R;                                         // 4MB
  u16*   kbp  = (u16*)(R + ((size_t)4 << 20));                   // 4MB
  u16*   vbp  = (u16*)(R + ((size_t)8 << 20));                   // 4MB
  u16*   ctx  = (u16*)(R + ((size_t)12 << 20));                  // 4MB
  float* x1   = (float*)(R + ((size_t)16 << 20));                // 8MB
  u16*   h2   = (u16*)(R + ((size_t)24 << 20));                  // 4MB
  u16*   act  = (u16*)(R + ((size_t)28 << 20));                  // 16MB
  float* pbuf = (float*)(R + ((size_t)44 << 20));                // 32MB (split-K partials)

  float* out0  = (float*)d_out;
  float* probs = (float*)d_out + 2097152;

  cvt_weights<<<16387, 256, 0, stream>>>(wq, wk, wv, wo, wg, wu, wd, wbf,
                                          bq, bk, bv, bqkv);

  // attn branch
  rmsnorm_kernel<<<2048, 256, 0, stream>>>(x, anw, h1);
  gemm_bt<64, 128, 1, true, false, false><<<dim3(24, 32), 256, 0, stream>>>(
      h1, wbf, nullptr, bqkv, nullptr, 2048, 3072, 1024, 1024, qbp, kbp, vbp);
  attn_kernel<<<1024, 256, 0, stream>>>(qbp, kbp, vbp, probs, ctx);
  gemm_bt<64, 128, 0, true, true, false><<<dim3(8, 32), 256, 0, stream>>>(
      ctx, wbf + ((size_t)3 << 20), x1, bo, x, 2048, 1024, 1024, 1024,
      nullptr, nullptr, nullptr);

  // ffn branch
  rmsnorm_kernel<<<2048, 256, 0, stream>>>(x1, fnw, h2);
  gemm_bt<128, 128, 2, false, false, false><<<dim3(64, 16), 256, 0, stream>>>(
      h2, wbf + ((size_t)4 << 20), nullptr, nullptr, nullptr, 2048, 8192, 1024, 1024,
      act, nullptr, nullptr);
  gemm_bt<64, 128, 0, false, false, true><<<dim3(8, 32, 4), 256, 0, stream>>>(
      act, wbf + ((size_t)12 << 20), pbuf, nullptr, nullptr, 2048, 1024, 1024, 4096,
      nullptr, nullptr, nullptr);
  reduce4_kernel<<<2048, 256, 0, stream>>>(pbuf, x1, out0);
}